// Round 1
// 863.803 us; speedup vs baseline: 1.1213x; 1.1213x over previous
//
#include <hip/hip_runtime.h>
#include <hip/hip_fp16.h>

// ---------------------------------------------------------------------------
// PoseProjection: T = inv(current) @ historical; trilinear grid_sample of
// features[8,32,48,96,96], sdf[8,1,...], occ[8,1,...] at the transformed
// voxel grid; also outputs the normalized grid [8,48,96,96,3].
// Outputs concatenated: feat(113246208) | sdf(3538944) | occ(3538944) | grid(10616832)
//
// R6: sparsity-aware staging. Poses are Haar-random rotations about the box
// corner -> most source rows are never sampled with nonzero weight and most
// output voxels are fully OOB (reference zero-pads). Transpose is now one
// block per (b,z,y) source row with a conservative segment-vs-AABB test
// (back-projected row centerline vs output box dilated by 1.5 > sqrt(2));
// untouched rows do zero traffic. proj2 guards every so_dup/feat_h4 gather
// with (weight != 0), which both skips wasted clamped-edge loads and makes
// unstaged (poisoned) rows unreachable. Bit-exact vs R5 (only removes +=x*0).
// Predicted: transpose traffic x f (f ~ 0.3-0.5), dur 968 -> ~800-880 us.
// ---------------------------------------------------------------------------

#define XD 96
#define YD 96
#define ZD 48
#define BD 8
#define CD 32

constexpr float VOX = 0.0625f;
constexpr int   HW   = YD * XD;          // 9216
constexpr int   DHW  = ZD * HW;          // 442368
constexpr long long FEAT_N = (long long)BD * CD * DHW;  // 113246208
constexpr long long SDF_N  = (long long)BD * DHW;       // 3538944
constexpr long long GRID_OFF = FEAT_N + 2 * SDF_N;

__device__ __forceinline__ unsigned h2u(__half2 h) {
    union { __half2 h; unsigned u; } c; c.h = h; return c.u;
}
__device__ __forceinline__ __half2 u2h(unsigned u) {
    union { unsigned u; __half2 h; } c; c.u = u; return c.h;
}

// --- Kernel 1: per-batch transform via double-precision adjugate inverse ---
__global__ void make_transform_kernel(const float* __restrict__ hist,
                                      const float* __restrict__ cur,
                                      float* __restrict__ T12) {
    int b = threadIdx.x;
    if (b >= BD) return;
    double m[16], inv[16];
    #pragma unroll
    for (int i = 0; i < 16; ++i) m[i] = (double)cur[b * 16 + i];

    inv[0]  =  m[5]*m[10]*m[15] - m[5]*m[11]*m[14] - m[9]*m[6]*m[15] + m[9]*m[7]*m[14] + m[13]*m[6]*m[11] - m[13]*m[7]*m[10];
    inv[4]  = -m[4]*m[10]*m[15] + m[4]*m[11]*m[14] + m[8]*m[6]*m[15] - m[8]*m[7]*m[14] - m[12]*m[6]*m[11] + m[12]*m[7]*m[10];
    inv[8]  =  m[4]*m[9]*m[15]  - m[4]*m[11]*m[13] - m[8]*m[5]*m[15] + m[8]*m[7]*m[13] + m[12]*m[5]*m[11] - m[12]*m[7]*m[9];
    inv[12] = -m[4]*m[9]*m[14]  + m[4]*m[10]*m[13] + m[8]*m[5]*m[14] - m[8]*m[6]*m[13] - m[12]*m[5]*m[10] + m[12]*m[6]*m[9];
    inv[1]  = -m[1]*m[10]*m[15] + m[1]*m[11]*m[14] + m[9]*m[2]*m[15] - m[9]*m[3]*m[14] - m[13]*m[2]*m[11] + m[13]*m[3]*m[10];
    inv[5]  =  m[0]*m[10]*m[15] - m[0]*m[11]*m[14] - m[8]*m[2]*m[15] + m[8]*m[3]*m[14] + m[12]*m[2]*m[11] - m[12]*m[3]*m[10];
    inv[9]  = -m[0]*m[9]*m[15]  + m[0]*m[11]*m[13] + m[8]*m[1]*m[15] - m[8]*m[3]*m[13] - m[12]*m[1]*m[11] + m[12]*m[3]*m[9];
    inv[13] =  m[0]*m[9]*m[14]  - m[0]*m[10]*m[13] - m[8]*m[1]*m[14] + m[8]*m[2]*m[13] + m[12]*m[1]*m[10] - m[12]*m[2]*m[9];
    inv[2]  =  m[1]*m[6]*m[15]  - m[1]*m[7]*m[14]  - m[5]*m[2]*m[15] + m[5]*m[3]*m[14] + m[13]*m[2]*m[7]  - m[13]*m[3]*m[6];
    inv[6]  = -m[0]*m[6]*m[15]  + m[0]*m[7]*m[14]  + m[4]*m[2]*m[15] - m[4]*m[3]*m[14] - m[12]*m[2]*m[7]  + m[12]*m[3]*m[6];
    inv[10] =  m[0]*m[5]*m[15]  - m[0]*m[7]*m[13]  - m[4]*m[1]*m[15] + m[4]*m[3]*m[13] + m[12]*m[1]*m[7]  - m[12]*m[3]*m[5];
    inv[14] = -m[0]*m[5]*m[14]  + m[0]*m[6]*m[13]  + m[4]*m[1]*m[14] - m[4]*m[2]*m[13] - m[12]*m[1]*m[6]  + m[12]*m[2]*m[5];
    inv[3]  = -m[1]*m[6]*m[11]  + m[1]*m[7]*m[10]  + m[5]*m[2]*m[11] - m[5]*m[3]*m[10] - m[9]*m[2]*m[7]   + m[9]*m[3]*m[6];
    inv[7]  =  m[0]*m[6]*m[11]  - m[0]*m[7]*m[10]  - m[4]*m[2]*m[11] + m[4]*m[3]*m[10] + m[8]*m[2]*m[7]   - m[8]*m[3]*m[6];
    inv[11] = -m[0]*m[5]*m[11]  + m[0]*m[7]*m[9]   + m[4]*m[1]*m[11] - m[4]*m[3]*m[9]  - m[8]*m[1]*m[7]   + m[8]*m[3]*m[5];
    inv[15] =  m[0]*m[5]*m[10]  - m[0]*m[6]*m[9]   - m[4]*m[1]*m[10] + m[4]*m[2]*m[9]  + m[8]*m[1]*m[6]   - m[8]*m[2]*m[5];

    double det = m[0]*inv[0] + m[1]*inv[4] + m[2]*inv[8] + m[3]*inv[12];
    double rdet = 1.0 / det;
    #pragma unroll
    for (int i = 0; i < 16; ++i) inv[i] *= rdet;

    #pragma unroll
    for (int i = 0; i < 3; ++i) {
        #pragma unroll
        for (int j = 0; j < 4; ++j) {
            double s = 0.0;
            #pragma unroll
            for (int k = 0; k < 4; ++k)
                s += inv[i * 4 + k] * (double)hist[b * 16 + k * 4 + j];
            T12[b * 12 + i * 4 + j] = (float)s;
        }
    }
}

// --- Conservative "is source row (y,z) ever sampled with nonzero weight?" ---
// Index-space map: i = M*v + t, M = T12 3x3 rows (orthonormal, rigid poses),
// t = Tb[3,7,11]/VOX. Row support = [-1,96]x[y-1,y+1]x[z-1,z+1]; its preimage
// under the rotation lies within L2 sqrt(2) of the back-projected centerline
// segment. Slab-test that segment against the output box dilated by 1.5.
__device__ __forceinline__ bool row_touched(const float* __restrict__ Tb,
                                            float y, float z) {
    const float inv_vox = 1.0f / VOX;
    const float tx = Tb[3]  * inv_vox;
    const float ty = Tb[7]  * inv_vox;
    const float tz = Tb[11] * inv_vox;
    const float uy = y - ty, uz = z - tz;
    const float ax0 = -1.0f - tx, ax1 = 96.0f - tx;
    const float byx = Tb[4] * uy + Tb[8]  * uz;
    const float byy = Tb[5] * uy + Tb[9]  * uz;
    const float byz = Tb[6] * uy + Tb[10] * uz;
    const float p0[3] = { Tb[0] * ax0 + byx, Tb[1] * ax0 + byy, Tb[2] * ax0 + byz };
    const float p1[3] = { Tb[0] * ax1 + byx, Tb[1] * ax1 + byy, Tb[2] * ax1 + byz };
    const float lo[3] = { -1.5f, -1.5f, -1.5f };
    const float hi[3] = { 96.5f, 96.5f, 48.5f };

    float t0 = 0.0f, t1 = 1.0f;
    #pragma unroll
    for (int a = 0; a < 3; ++a) {
        const float d = p1[a] - p0[a];
        if (fabsf(d) < 1e-5f) {
            if (p0[a] < lo[a] || p0[a] > hi[a]) return false;
        } else {
            const float ra = (lo[a] - p0[a]) / d;
            const float rb = (hi[a] - p0[a]) / d;
            t0 = fmaxf(t0, fminf(ra, rb));
            t1 = fminf(t1, fmaxf(ra, rb));
        }
    }
    return t0 <= t1;
}

// --- Pass A: per-row channels-last fp16 staging, skipping untouched rows ---
__global__ __launch_bounds__(256) void transpose_kernel(
    const float4* __restrict__ feat4,
    const float* __restrict__ sdf,
    const float* __restrict__ occ,
    const float* __restrict__ T12,
    uint4* __restrict__ feat_h4,      // [B*DHW][4] : 4 x (8 halfs)
    uint2* __restrict__ so_dup) {     // [B*DHW] : {h2(sdf,occ)@v, h2@v+1}

    __shared__ float tile[CD][100];   // stride 400 B: float4-aligned rows

    const int bid = blockIdx.x;
    const int b   = bid & 7;                 // XCD-batch swizzle
    const int rg  = bid >> 3;                // source row index: z*96+y
    const float* Tb = T12 + b * 12;

    if (!row_touched(Tb, (float)(rg % YD), (float)(rg / YD))) return;

    const int tid     = threadIdx.x;
    const int rowbase = rg * XD;

    // read: 32 channels x 24 float4 (96 floats) each, lanes contiguous in x
    #pragma unroll
    for (int it = 0; it < 3; ++it) {
        const int idx = it * 256 + tid;      // 0..767
        const int c   = idx / 24;
        const int x4  = idx - c * 24;
        float4 r = feat4[(((size_t)(b * CD + c) * DHW + rowbase) >> 2) + x4];
        *(float4*)&tile[c][x4 * 4] = r;
    }
    if (tid < XD) {
        const size_t v  = (size_t)b * DHW + rowbase + tid;
        const size_t v1 = (v + 1 < (size_t)BD * DHW) ? v + 1 : v;
        uint2 sd;
        sd.x = h2u(__float22half2_rn(make_float2(sdf[v],  occ[v])));
        sd.y = h2u(__float22half2_rn(make_float2(sdf[v1], occ[v1])));
        so_dup[v] = sd;
    }
    __syncthreads();

    // write: channels-last fp16; consecutive idx -> consecutive uint4
    const size_t ob = (size_t)b * DHW + rowbase;
    #pragma unroll
    for (int it = 0; it < 2; ++it) {
        const int idx = it * 256 + tid;      // need 0..383
        if (idx < XD * 4) {
            const int v  = idx >> 2;
            const int c8 = idx & 3;
            float f0 = tile[c8 * 8 + 0][v], f1 = tile[c8 * 8 + 1][v];
            float f2 = tile[c8 * 8 + 2][v], f3 = tile[c8 * 8 + 3][v];
            float f4 = tile[c8 * 8 + 4][v], f5 = tile[c8 * 8 + 5][v];
            float f6 = tile[c8 * 8 + 6][v], f7 = tile[c8 * 8 + 7][v];
            uint4 o;
            o.x = h2u(__float22half2_rn(make_float2(f0, f1)));
            o.y = h2u(__float22half2_rn(make_float2(f2, f3)));
            o.z = h2u(__float22half2_rn(make_float2(f4, f5)));
            o.w = h2u(__float22half2_rn(make_float2(f6, f7)));
            feat_h4[(ob + v) * 4 + c8] = o;
        }
    }
}

// --- Pass B: paired fp16 gather; octet = 2 x-sides x 4 channel-groups ---
// All gathers guarded by (weight != 0): skips clamped-edge waste and makes
// unstaged (skipped-row) data unreachable.
__global__ __launch_bounds__(256, 4) void proj2_kernel(
    const uint4* __restrict__ feat_h4,
    const uint2* __restrict__ so_dup,
    const float* __restrict__ T12,
    float* __restrict__ out) {

    __shared__ float4 ow4[256][4];    // per voxel, per (dy,dz) pair: off,wl,wh
    __shared__ float  tile[128][33];  // results for one 128-voxel sub-tile
    __shared__ float  gbuf[768];      // grid coords staging

    const int bid   = blockIdx.x;
    const int b     = bid & 7;                 // XCD-batch swizzle
    const int vbase = (bid >> 3) * 256;
    const int tid   = threadIdx.x;
    const int bDHW  = b * DHW;

    // ---- Phase 1: per-voxel coords, pair descriptors, sdf/occ gather ----
    {
        const int v  = vbase + tid;
        const int x  = v % XD;
        const int t1 = v / XD;
        const int y  = t1 % YD;
        const int z  = t1 / YD;

        const float* Tb = T12 + b * 12;
        const float px = x * VOX, py = y * VOX, pz = z * VOX;
        const float hx = Tb[0] * px + Tb[1] * py + Tb[2]  * pz + Tb[3];
        const float hy = Tb[4] * px + Tb[5] * py + Tb[6]  * pz + Tb[7];
        const float hz = Tb[8] * px + Tb[9] * py + Tb[10] * pz + Tb[11];

        const float nx = 2.0f * ((hx / VOX) / 95.0f) - 1.0f;
        const float ny = 2.0f * ((hy / VOX) / 95.0f) - 1.0f;
        const float nz = 2.0f * ((hz / VOX) / 47.0f) - 1.0f;

        gbuf[tid * 3 + 0] = nx;
        gbuf[tid * 3 + 1] = ny;
        gbuf[tid * 3 + 2] = nz;

        const float ix = (nx + 1.0f) * 0.5f * 95.0f;
        const float iy = (ny + 1.0f) * 0.5f * 95.0f;
        const float iz = (nz + 1.0f) * 0.5f * 47.0f;

        const float x0f = floorf(ix), y0f = floorf(iy), z0f = floorf(iz);
        const float fx = ix - x0f, fy = iy - y0f, fz = iz - z0f;

        const float wXa[2] = {1.0f - fx, fx};
        const float wYa[2] = {1.0f - fy, fy};
        const float wZa[2] = {1.0f - fz, fz};

        int  cX[2], cY[2], cZ[2];
        bool vX[2], vY[2], vZ[2];
        #pragma unroll
        for (int d = 0; d < 2; ++d) {
            const float xi = x0f + (float)d;
            const float yi = y0f + (float)d;
            const float zi = z0f + (float)d;
            vX[d] = (xi >= 0.0f) && (xi <= 95.0f);
            vY[d] = (yi >= 0.0f) && (yi <= 95.0f);
            vZ[d] = (zi >= 0.0f) && (zi <= 47.0f);
            cX[d] = (int)fminf(fmaxf(xi, 0.0f), 95.0f);
            cY[d] = (int)fminf(fmaxf(yi, 0.0f), 95.0f);
            cZ[d] = (int)fminf(fmaxf(zi, 0.0f), 47.0f);
        }

        // x-pair remap to base blo in [0,94]; weights assigned by absolute x
        const float w0 = vX[0] ? wXa[0] : 0.0f;
        const float w1 = vX[1] ? wXa[1] : 0.0f;
        const int   blo = (cX[0] < 94) ? cX[0] : 94;
        const float wl = ((cX[0] == blo) ? w0 : 0.0f) + ((cX[1] == blo) ? w1 : 0.0f);
        const float wh = ((cX[0] == blo + 1) ? w0 : 0.0f) + ((cX[1] == blo + 1) ? w1 : 0.0f);

        float2 a2 = make_float2(0.f, 0.f);
        #pragma unroll
        for (int p = 0; p < 4; ++p) {
            const int dy = p & 1, dz = p >> 1;
            float wyz = wYa[dy] * wZa[dz];
            wyz = (vY[dy] && vZ[dz]) ? wyz : 0.0f;
            const float wlp = wl * wyz, whp = wh * wyz;
            const int offp = bDHW + cZ[dz] * HW + cY[dy] * XD + blo;
            ow4[tid][p] = make_float4(__int_as_float(offp), wlp, whp, 0.0f);

            if (wlp != 0.0f || whp != 0.0f) {
                const uint2 sd = so_dup[(size_t)offp];
                const float2 s0 = __half22float2(u2h(sd.x));
                const float2 s1 = __half22float2(u2h(sd.y));
                a2.x += s0.x * wlp + s1.x * whp;
                a2.y += s0.y * wlp + s1.y * whp;
            }
        }
        out[FEAT_N + (size_t)bDHW + v]         = a2.x;   // sdf (coalesced)
        out[FEAT_N + SDF_N + (size_t)bDHW + v] = a2.y;   // occ (coalesced)
    }
    __syncthreads();

    // ---- grid output: 768 consecutive floats -> 192 float4 stores ----
    if (tid < 192) {
        float4 gv = *(const float4*)&gbuf[tid * 4];
        *(float4*)(out + GRID_OFF + ((size_t)bDHW + vbase) * 3 + tid * 4) = gv;
    }

    // ---- Phase 2: paired gather. octet lane = (x-side, channel-8-group) ----
    const int ovb  = tid >> 3;          // voxel slot 0..31 per pass
    const int l    = tid & 7;
    const int side = l >> 2;            // 0 = x-lo, 1 = x-hi
    const int cq   = l & 3;             // 8-channel group
    float* ob = out + (size_t)b * CD * DHW + vbase;

    #pragma unroll
    for (int h = 0; h < 2; ++h) {
        #pragma unroll 2
        for (int it = 0; it < 4; ++it) {
            const int vl = it * 32 + ovb;         // 0..127 sub-tile local
            const int ov = h * 128 + vl;          // block voxel
            float acc[8] = {0.f, 0.f, 0.f, 0.f, 0.f, 0.f, 0.f, 0.f};
            #pragma unroll
            for (int p = 0; p < 4; ++p) {
                const float4 d = ow4[ov][p];      // octet broadcast
                if (d.y == 0.0f && d.z == 0.0f) continue;   // pair weight 0
                const int offp = __float_as_int(d.x);
                const float w  = side ? d.z : d.y;
                const uint4 fv = feat_h4[(size_t)offp * 4 + l];  // 16B: side*64+cq*16
                float2 f;
                f = __half22float2(u2h(fv.x)); acc[0] += f.x * w; acc[1] += f.y * w;
                f = __half22float2(u2h(fv.y)); acc[2] += f.x * w; acc[3] += f.y * w;
                f = __half22float2(u2h(fv.z)); acc[4] += f.x * w; acc[5] += f.y * w;
                f = __half22float2(u2h(fv.w)); acc[6] += f.x * w; acc[7] += f.y * w;
            }
            #pragma unroll
            for (int k = 0; k < 8; ++k) acc[k] += __shfl_xor(acc[k], 4);
            if (side == 0) {
                #pragma unroll
                for (int k = 0; k < 8; ++k) tile[vl][cq * 8 + k] = acc[k];
            }
        }
        __syncthreads();

        // coalesced float4 stores of this 128-voxel sub-tile
        #pragma unroll
        for (int it2 = 0; it2 < 4; ++it2) {
            const int idx = it2 * 256 + tid;
            const int v32 = idx & 31;
            const int c   = idx >> 5;
            float4 w;
            w.x = tile[v32 * 4 + 0][c];
            w.y = tile[v32 * 4 + 1][c];
            w.z = tile[v32 * 4 + 2][c];
            w.w = tile[v32 * 4 + 3][c];
            *(float4*)&ob[(size_t)c * DHW + h * 128 + v32 * 4] = w;
        }
        __syncthreads();
    }
}

// --- Fallback (R1 kernel) if workspace is too small ---
__global__ __launch_bounds__(256) void proj_kernel(
    const float* __restrict__ feat,
    const float* __restrict__ sdf,
    const float* __restrict__ occ,
    const float* __restrict__ T12,
    float* __restrict__ out) {

    const int b   = blockIdx.x / (DHW / 256);
    const int rem = blockIdx.x % (DHW / 256);
    const int zyx = rem * 256 + threadIdx.x;
    const int x   = zyx % XD;
    const int t1  = zyx / XD;
    const int y   = t1 % YD;
    const int z   = t1 / YD;

    const float* Tb = T12 + b * 12;
    const float px = x * VOX, py = y * VOX, pz = z * VOX;
    const float hx = Tb[0] * px + Tb[1] * py + Tb[2]  * pz + Tb[3];
    const float hy = Tb[4] * px + Tb[5] * py + Tb[6]  * pz + Tb[7];
    const float hz = Tb[8] * px + Tb[9] * py + Tb[10] * pz + Tb[11];

    const float nx = 2.0f * ((hx / VOX) / 95.0f) - 1.0f;
    const float ny = 2.0f * ((hy / VOX) / 95.0f) - 1.0f;
    const float nz = 2.0f * ((hz / VOX) / 47.0f) - 1.0f;

    {
        const long long gbase = GRID_OFF + ((long long)b * DHW + zyx) * 3;
        out[gbase + 0] = nx;
        out[gbase + 1] = ny;
        out[gbase + 2] = nz;
    }

    const float ix = (nx + 1.0f) * 0.5f * 95.0f;
    const float iy = (ny + 1.0f) * 0.5f * 95.0f;
    const float iz = (nz + 1.0f) * 0.5f * 47.0f;

    const float x0f = floorf(ix), y0f = floorf(iy), z0f = floorf(iz);
    const float fx = ix - x0f, fy = iy - y0f, fz = iz - z0f;

    const float wXa[2] = {1.0f - fx, fx};
    const float wYa[2] = {1.0f - fy, fy};
    const float wZa[2] = {1.0f - fz, fz};

    int  cX[2], cY[2], cZ[2];
    bool vX[2], vY[2], vZ[2];
    #pragma unroll
    for (int d = 0; d < 2; ++d) {
        const float xi = x0f + (float)d;
        const float yi = y0f + (float)d;
        const float zi = z0f + (float)d;
        vX[d] = (xi >= 0.0f) && (xi <= 95.0f);
        vY[d] = (yi >= 0.0f) && (yi <= 95.0f);
        vZ[d] = (zi >= 0.0f) && (zi <= 47.0f);
        cX[d] = (int)fminf(fmaxf(xi, 0.0f), 95.0f);
        cY[d] = (int)fminf(fmaxf(yi, 0.0f), 95.0f);
        cZ[d] = (int)fminf(fmaxf(zi, 0.0f), 47.0f);
    }

    int   offs[8];
    float wts[8];
    #pragma unroll
    for (int j = 0; j < 8; ++j) {
        const int dx = (j >> 2) & 1, dy = (j >> 1) & 1, dz = j & 1;
        offs[j] = cZ[dz] * HW + cY[dy] * XD + cX[dx];
        float w = (wXa[dx] * wYa[dy]) * wZa[dz];
        wts[j] = (vX[dx] && vY[dy] && vZ[dz]) ? w : 0.0f;
    }

    const float* fb = feat + (long long)b * CD * DHW;
    float* ob = out + (long long)b * CD * DHW + zyx;
    #pragma unroll 4
    for (int cc = 0; cc < CD; ++cc) {
        const float* p = fb + (long long)cc * DHW;
        float acc = 0.0f;
        #pragma unroll
        for (int j = 0; j < 8; ++j) acc += p[offs[j]] * wts[j];
        ob[(long long)cc * DHW] = acc;
    }
    {
        const float* p = sdf + (long long)b * DHW;
        float acc = 0.0f;
        #pragma unroll
        for (int j = 0; j < 8; ++j) acc += p[offs[j]] * wts[j];
        out[FEAT_N + (long long)b * DHW + zyx] = acc;
    }
    {
        const float* p = occ + (long long)b * DHW;
        float acc = 0.0f;
        #pragma unroll
        for (int j = 0; j < 8; ++j) acc += p[offs[j]] * wts[j];
        out[FEAT_N + SDF_N + (long long)b * DHW + zyx] = acc;
    }
}

extern "C" void kernel_launch(void* const* d_in, const int* in_sizes, int n_in,
                              void* d_out, int out_size, void* d_ws, size_t ws_size,
                              hipStream_t stream) {
    const float* feat = (const float*)d_in[0];
    const float* sdf  = (const float*)d_in[1];
    const float* occ  = (const float*)d_in[2];
    const float* hist = (const float*)d_in[3];
    const float* cur  = (const float*)d_in[4];
    float* out = (float*)d_out;

    // ws layout: feat_h (FEAT_N halfs) | so_dup (B*DHW uint2) | T12
    const size_t feat_h_bytes = (size_t)FEAT_N * 2;                 // ~226.5 MB
    const size_t so_bytes     = (size_t)BD * DHW * sizeof(uint2);   // ~28.3 MB
    const size_t need         = feat_h_bytes + so_bytes + 512;

    if (ws_size >= need) {
        uint4* feat_h4 = (uint4*)d_ws;
        uint2* so_dup  = (uint2*)((char*)d_ws + feat_h_bytes);
        float* T12     = (float*)((char*)d_ws + feat_h_bytes + so_bytes);

        make_transform_kernel<<<1, BD, 0, stream>>>(hist, cur, T12);
        transpose_kernel<<<BD * ZD * YD, 256, 0, stream>>>(
            (const float4*)feat, sdf, occ, T12, feat_h4, so_dup);
        proj2_kernel<<<BD * (DHW / 256), 256, 0, stream>>>(
            (const uint4*)feat_h4, (const uint2*)so_dup, T12, out);
    } else {
        float* T12 = (float*)d_ws;
        make_transform_kernel<<<1, BD, 0, stream>>>(hist, cur, T12);
        proj_kernel<<<BD * (DHW / 256), 256, 0, stream>>>(feat, sdf, occ, T12, out);
    }
}

// Round 3
// 774.045 us; speedup vs baseline: 1.2514x; 1.1160x over previous
//
#include <hip/hip_runtime.h>
#include <hip/hip_fp16.h>

// ---------------------------------------------------------------------------
// PoseProjection: T = inv(current) @ historical; trilinear grid_sample of
// features[8,32,48,96,96], sdf[8,1,...], occ[8,1,...] at the transformed
// voxel grid; also outputs the normalized grid [8,48,96,96,3].
// Outputs concatenated: feat(113246208) | sdf(3538944) | occ(3538944) | grid(10616832)
//
// R8 == R7 resubmit (R7 bench died to an infra "container failed twice").
// R7: proj2 de-bloat. (1) All-OOB blocks (majority under Haar-random poses)
// detected via ballot vote -> skip phase 2, stream zeros with NT float4
// stores. (2) All out-writes nontemporal: out is 523 MB write-once; keeping
// it out of L2/L3 preserves cache for feat_h4/so_dup gather reuse. (3)
// per-voxel skip flag in ow4[v][0].w. Staging writes stay cached (re-read by
// proj2). Bit-exact vs R6. Predicted: proj2 ~250 -> ~170 us, dur ~780-805.
// ---------------------------------------------------------------------------

#define XD 96
#define YD 96
#define ZD 48
#define BD 8
#define CD 32

constexpr float VOX = 0.0625f;
constexpr int   HW   = YD * XD;          // 9216
constexpr int   DHW  = ZD * HW;          // 442368
constexpr long long FEAT_N = (long long)BD * CD * DHW;  // 113246208
constexpr long long SDF_N  = (long long)BD * DHW;       // 3538944
constexpr long long GRID_OFF = FEAT_N + 2 * SDF_N;

typedef float f32x4 __attribute__((ext_vector_type(4)));

__device__ __forceinline__ unsigned h2u(__half2 h) {
    union { __half2 h; unsigned u; } c; c.h = h; return c.u;
}
__device__ __forceinline__ __half2 u2h(unsigned u) {
    union { unsigned u; __half2 h; } c; c.u = u; return c.h;
}
__device__ __forceinline__ void nt_store4(float* p, float a, float b, float c, float d) {
    f32x4 v = {a, b, c, d};
    __builtin_nontemporal_store(v, (f32x4*)p);
}
__device__ __forceinline__ void nt_store1(float* p, float v) {
    __builtin_nontemporal_store(v, p);
}

// --- Kernel 1: per-batch transform via double-precision adjugate inverse ---
__global__ void make_transform_kernel(const float* __restrict__ hist,
                                      const float* __restrict__ cur,
                                      float* __restrict__ T12) {
    int b = threadIdx.x;
    if (b >= BD) return;
    double m[16], inv[16];
    #pragma unroll
    for (int i = 0; i < 16; ++i) m[i] = (double)cur[b * 16 + i];

    inv[0]  =  m[5]*m[10]*m[15] - m[5]*m[11]*m[14] - m[9]*m[6]*m[15] + m[9]*m[7]*m[14] + m[13]*m[6]*m[11] - m[13]*m[7]*m[10];
    inv[4]  = -m[4]*m[10]*m[15] + m[4]*m[11]*m[14] + m[8]*m[6]*m[15] - m[8]*m[7]*m[14] - m[12]*m[6]*m[11] + m[12]*m[7]*m[10];
    inv[8]  =  m[4]*m[9]*m[15]  - m[4]*m[11]*m[13] - m[8]*m[5]*m[15] + m[8]*m[7]*m[13] + m[12]*m[5]*m[11] - m[12]*m[7]*m[9];
    inv[12] = -m[4]*m[9]*m[14]  + m[4]*m[10]*m[13] + m[8]*m[5]*m[14] - m[8]*m[6]*m[13] - m[12]*m[5]*m[10] + m[12]*m[6]*m[9];
    inv[1]  = -m[1]*m[10]*m[15] + m[1]*m[11]*m[14] + m[9]*m[2]*m[15] - m[9]*m[3]*m[14] - m[13]*m[2]*m[11] + m[13]*m[3]*m[10];
    inv[5]  =  m[0]*m[10]*m[15] - m[0]*m[11]*m[14] - m[8]*m[2]*m[15] + m[8]*m[3]*m[14] + m[12]*m[2]*m[11] - m[12]*m[3]*m[10];
    inv[9]  = -m[0]*m[9]*m[15]  + m[0]*m[11]*m[13] + m[8]*m[1]*m[15] - m[8]*m[3]*m[13] - m[12]*m[1]*m[11] + m[12]*m[3]*m[9];
    inv[13] =  m[0]*m[9]*m[14]  - m[0]*m[10]*m[13] - m[8]*m[1]*m[14] + m[8]*m[2]*m[13] + m[12]*m[1]*m[10] - m[12]*m[2]*m[9];
    inv[2]  =  m[1]*m[6]*m[15]  - m[1]*m[7]*m[14]  - m[5]*m[2]*m[15] + m[5]*m[3]*m[14] + m[13]*m[2]*m[7]  - m[13]*m[3]*m[6];
    inv[6]  = -m[0]*m[6]*m[15]  + m[0]*m[7]*m[14]  + m[4]*m[2]*m[15] - m[4]*m[3]*m[14] - m[12]*m[2]*m[7]  + m[12]*m[3]*m[6];
    inv[10] =  m[0]*m[5]*m[15]  - m[0]*m[7]*m[13]  - m[4]*m[1]*m[15] + m[4]*m[3]*m[13] + m[12]*m[1]*m[7]  - m[12]*m[3]*m[5];
    inv[14] = -m[0]*m[5]*m[14]  + m[0]*m[6]*m[13]  + m[4]*m[1]*m[14] - m[4]*m[2]*m[13] - m[12]*m[1]*m[6]  + m[12]*m[2]*m[5];
    inv[3]  = -m[1]*m[6]*m[11]  + m[1]*m[7]*m[10]  + m[5]*m[2]*m[11] - m[5]*m[3]*m[10] - m[9]*m[2]*m[7]   + m[9]*m[3]*m[6];
    inv[7]  =  m[0]*m[6]*m[11]  - m[0]*m[7]*m[10]  - m[4]*m[2]*m[11] + m[4]*m[3]*m[10] + m[8]*m[2]*m[7]   - m[8]*m[3]*m[6];
    inv[11] = -m[0]*m[5]*m[11]  + m[0]*m[7]*m[9]   + m[4]*m[1]*m[11] - m[4]*m[3]*m[9]  - m[8]*m[1]*m[7]   + m[8]*m[3]*m[5];
    inv[15] =  m[0]*m[5]*m[10]  - m[0]*m[6]*m[9]   - m[4]*m[1]*m[10] + m[4]*m[2]*m[9]  + m[8]*m[1]*m[6]   - m[8]*m[2]*m[5];

    double det = m[0]*inv[0] + m[1]*inv[4] + m[2]*inv[8] + m[3]*inv[12];
    double rdet = 1.0 / det;
    #pragma unroll
    for (int i = 0; i < 16; ++i) inv[i] *= rdet;

    #pragma unroll
    for (int i = 0; i < 3; ++i) {
        #pragma unroll
        for (int j = 0; j < 4; ++j) {
            double s = 0.0;
            #pragma unroll
            for (int k = 0; k < 4; ++k)
                s += inv[i * 4 + k] * (double)hist[b * 16 + k * 4 + j];
            T12[b * 12 + i * 4 + j] = (float)s;
        }
    }
}

// --- Conservative "is source row (y,z) ever sampled with nonzero weight?" ---
// Index-space map: i = M*v + t, M = T12 3x3 rows (orthonormal, rigid poses),
// t = Tb[3,7,11]/VOX. Row support = [-1,96]x[y-1,y+1]x[z-1,z+1]; its preimage
// under the rotation lies within L2 sqrt(2) of the back-projected centerline
// segment. Slab-test that segment against the output box dilated by 1.5.
__device__ __forceinline__ bool row_touched(const float* __restrict__ Tb,
                                            float y, float z) {
    const float inv_vox = 1.0f / VOX;
    const float tx = Tb[3]  * inv_vox;
    const float ty = Tb[7]  * inv_vox;
    const float tz = Tb[11] * inv_vox;
    const float uy = y - ty, uz = z - tz;
    const float ax0 = -1.0f - tx, ax1 = 96.0f - tx;
    const float byx = Tb[4] * uy + Tb[8]  * uz;
    const float byy = Tb[5] * uy + Tb[9]  * uz;
    const float byz = Tb[6] * uy + Tb[10] * uz;
    const float p0[3] = { Tb[0] * ax0 + byx, Tb[1] * ax0 + byy, Tb[2] * ax0 + byz };
    const float p1[3] = { Tb[0] * ax1 + byx, Tb[1] * ax1 + byy, Tb[2] * ax1 + byz };
    const float lo[3] = { -1.5f, -1.5f, -1.5f };
    const float hi[3] = { 96.5f, 96.5f, 48.5f };

    float t0 = 0.0f, t1 = 1.0f;
    #pragma unroll
    for (int a = 0; a < 3; ++a) {
        const float d = p1[a] - p0[a];
        if (fabsf(d) < 1e-5f) {
            if (p0[a] < lo[a] || p0[a] > hi[a]) return false;
        } else {
            const float ra = (lo[a] - p0[a]) / d;
            const float rb = (hi[a] - p0[a]) / d;
            t0 = fmaxf(t0, fminf(ra, rb));
            t1 = fminf(t1, fmaxf(ra, rb));
        }
    }
    return t0 <= t1;
}

// --- Pass A: per-row channels-last fp16 staging, skipping untouched rows ---
__global__ __launch_bounds__(256) void transpose_kernel(
    const float4* __restrict__ feat4,
    const float* __restrict__ sdf,
    const float* __restrict__ occ,
    const float* __restrict__ T12,
    uint4* __restrict__ feat_h4,      // [B*DHW][4] : 4 x (8 halfs)
    uint2* __restrict__ so_dup) {     // [B*DHW] : {h2(sdf,occ)@v, h2@v+1}

    __shared__ float tile[CD][100];   // stride 400 B: float4-aligned rows

    const int bid = blockIdx.x;
    const int b   = bid & 7;                 // XCD-batch swizzle
    const int rg  = bid >> 3;                // source row index: z*96+y
    const float* Tb = T12 + b * 12;

    if (!row_touched(Tb, (float)(rg % YD), (float)(rg / YD))) return;

    const int tid     = threadIdx.x;
    const int rowbase = rg * XD;

    // read: 32 channels x 24 float4 (96 floats) each, lanes contiguous in x
    #pragma unroll
    for (int it = 0; it < 3; ++it) {
        const int idx = it * 256 + tid;      // 0..767
        const int c   = idx / 24;
        const int x4  = idx - c * 24;
        float4 r = feat4[(((size_t)(b * CD + c) * DHW + rowbase) >> 2) + x4];
        *(float4*)&tile[c][x4 * 4] = r;
    }
    if (tid < XD) {
        const size_t v  = (size_t)b * DHW + rowbase + tid;
        const size_t v1 = (v + 1 < (size_t)BD * DHW) ? v + 1 : v;
        uint2 sd;
        sd.x = h2u(__float22half2_rn(make_float2(sdf[v],  occ[v])));
        sd.y = h2u(__float22half2_rn(make_float2(sdf[v1], occ[v1])));
        so_dup[v] = sd;
    }
    __syncthreads();

    // write: channels-last fp16; consecutive idx -> consecutive uint4
    const size_t ob = (size_t)b * DHW + rowbase;
    #pragma unroll
    for (int it = 0; it < 2; ++it) {
        const int idx = it * 256 + tid;      // need 0..383
        if (idx < XD * 4) {
            const int v  = idx >> 2;
            const int c8 = idx & 3;
            float f0 = tile[c8 * 8 + 0][v], f1 = tile[c8 * 8 + 1][v];
            float f2 = tile[c8 * 8 + 2][v], f3 = tile[c8 * 8 + 3][v];
            float f4 = tile[c8 * 8 + 4][v], f5 = tile[c8 * 8 + 5][v];
            float f6 = tile[c8 * 8 + 6][v], f7 = tile[c8 * 8 + 7][v];
            uint4 o;
            o.x = h2u(__float22half2_rn(make_float2(f0, f1)));
            o.y = h2u(__float22half2_rn(make_float2(f2, f3)));
            o.z = h2u(__float22half2_rn(make_float2(f4, f5)));
            o.w = h2u(__float22half2_rn(make_float2(f6, f7)));
            feat_h4[(ob + v) * 4 + c8] = o;
        }
    }
}

// --- Pass B: paired fp16 gather; octet = 2 x-sides x 4 channel-groups ---
// All gathers guarded by (weight != 0): skips clamped-edge waste and makes
// unstaged (skipped-row) data unreachable. All-OOB blocks take a pure
// streaming zero-store fast path. Output stores are nontemporal.
__global__ __launch_bounds__(256, 4) void proj2_kernel(
    const uint4* __restrict__ feat_h4,
    const uint2* __restrict__ so_dup,
    const float* __restrict__ T12,
    float* __restrict__ out) {

    __shared__ float4 ow4[256][4];    // per voxel, per (dy,dz) pair: off,wl,wh
    __shared__ float  tile[128][33];  // results for one 128-voxel sub-tile
    __shared__ float  gbuf[768];      // grid coords staging
    __shared__ unsigned long long s_any[4];

    const int bid   = blockIdx.x;
    const int b     = bid & 7;                 // XCD-batch swizzle
    const int vbase = (bid >> 3) * 256;
    const int tid   = threadIdx.x;
    const int bDHW  = b * DHW;

    // ---- Phase 1: per-voxel coords, pair descriptors, sdf/occ gather ----
    {
        const int v  = vbase + tid;
        const int x  = v % XD;
        const int t1 = v / XD;
        const int y  = t1 % YD;
        const int z  = t1 / YD;

        const float* Tb = T12 + b * 12;
        const float px = x * VOX, py = y * VOX, pz = z * VOX;
        const float hx = Tb[0] * px + Tb[1] * py + Tb[2]  * pz + Tb[3];
        const float hy = Tb[4] * px + Tb[5] * py + Tb[6]  * pz + Tb[7];
        const float hz = Tb[8] * px + Tb[9] * py + Tb[10] * pz + Tb[11];

        const float nx = 2.0f * ((hx / VOX) / 95.0f) - 1.0f;
        const float ny = 2.0f * ((hy / VOX) / 95.0f) - 1.0f;
        const float nz = 2.0f * ((hz / VOX) / 47.0f) - 1.0f;

        gbuf[tid * 3 + 0] = nx;
        gbuf[tid * 3 + 1] = ny;
        gbuf[tid * 3 + 2] = nz;

        const float ix = (nx + 1.0f) * 0.5f * 95.0f;
        const float iy = (ny + 1.0f) * 0.5f * 95.0f;
        const float iz = (nz + 1.0f) * 0.5f * 47.0f;

        const float x0f = floorf(ix), y0f = floorf(iy), z0f = floorf(iz);
        const float fx = ix - x0f, fy = iy - y0f, fz = iz - z0f;

        const float wXa[2] = {1.0f - fx, fx};
        const float wYa[2] = {1.0f - fy, fy};
        const float wZa[2] = {1.0f - fz, fz};

        int  cX[2], cY[2], cZ[2];
        bool vX[2], vY[2], vZ[2];
        #pragma unroll
        for (int d = 0; d < 2; ++d) {
            const float xi = x0f + (float)d;
            const float yi = y0f + (float)d;
            const float zi = z0f + (float)d;
            vX[d] = (xi >= 0.0f) && (xi <= 95.0f);
            vY[d] = (yi >= 0.0f) && (yi <= 95.0f);
            vZ[d] = (zi >= 0.0f) && (zi <= 47.0f);
            cX[d] = (int)fminf(fmaxf(xi, 0.0f), 95.0f);
            cY[d] = (int)fminf(fmaxf(yi, 0.0f), 95.0f);
            cZ[d] = (int)fminf(fmaxf(zi, 0.0f), 47.0f);
        }

        // x-pair remap to base blo in [0,94]; weights assigned by absolute x
        const float w0 = vX[0] ? wXa[0] : 0.0f;
        const float w1 = vX[1] ? wXa[1] : 0.0f;
        const int   blo = (cX[0] < 94) ? cX[0] : 94;
        const float wl = ((cX[0] == blo) ? w0 : 0.0f) + ((cX[1] == blo) ? w1 : 0.0f);
        const float wh = ((cX[0] == blo + 1) ? w0 : 0.0f) + ((cX[1] == blo + 1) ? w1 : 0.0f);

        bool anyv = false;
        float2 a2 = make_float2(0.f, 0.f);
        #pragma unroll
        for (int p = 0; p < 4; ++p) {
            const int dy = p & 1, dz = p >> 1;
            float wyz = wYa[dy] * wZa[dz];
            wyz = (vY[dy] && vZ[dz]) ? wyz : 0.0f;
            const float wlp = wl * wyz, whp = wh * wyz;
            const int offp = bDHW + cZ[dz] * HW + cY[dy] * XD + blo;
            ow4[tid][p] = make_float4(__int_as_float(offp), wlp, whp, 0.0f);

            if (wlp != 0.0f || whp != 0.0f) {
                anyv = true;
                const uint2 sd = so_dup[(size_t)offp];
                const float2 s0 = __half22float2(u2h(sd.x));
                const float2 s1 = __half22float2(u2h(sd.y));
                a2.x += s0.x * wlp + s1.x * whp;
                a2.y += s0.y * wlp + s1.y * whp;
            }
        }
        ow4[tid][0].w = anyv ? 1.0f : 0.0f;   // per-voxel skip flag

        const unsigned long long bal = __ballot(anyv);
        if ((tid & 63) == 0) s_any[tid >> 6] = bal;

        nt_store1(out + FEAT_N + (size_t)bDHW + v,         a2.x);  // sdf
        nt_store1(out + FEAT_N + SDF_N + (size_t)bDHW + v, a2.y);  // occ
    }
    __syncthreads();

    // ---- grid output: 768 consecutive floats -> 192 float4 stores ----
    if (tid < 192) {
        const float* g = &gbuf[tid * 4];
        nt_store4(out + GRID_OFF + ((size_t)bDHW + vbase) * 3 + tid * 4,
                  g[0], g[1], g[2], g[3]);
    }

    float* ob = out + (size_t)b * CD * DHW + vbase;

    // ---- All-OOB fast path: pure streaming zero-store, skip phase 2 ----
    if ((s_any[0] | s_any[1] | s_any[2] | s_any[3]) == 0ULL) {
        #pragma unroll
        for (int it = 0; it < 8; ++it) {
            const int idx = it * 256 + tid;   // 0..2047
            const int c   = idx >> 6;         // 0..31
            const int v4  = idx & 63;         // 0..63 float4s of 256 voxels
            nt_store4(&ob[(size_t)c * DHW + v4 * 4], 0.f, 0.f, 0.f, 0.f);
        }
        return;
    }

    // ---- Phase 2: paired gather. octet lane = (x-side, channel-8-group) ----
    const int ovb  = tid >> 3;          // voxel slot 0..31 per pass
    const int l    = tid & 7;
    const int side = l >> 2;            // 0 = x-lo, 1 = x-hi
    const int cq   = l & 3;             // 8-channel group

    #pragma unroll
    for (int h = 0; h < 2; ++h) {
        #pragma unroll 2
        for (int it = 0; it < 4; ++it) {
            const int vl = it * 32 + ovb;         // 0..127 sub-tile local
            const int ov = h * 128 + vl;          // block voxel
            float acc[8] = {0.f, 0.f, 0.f, 0.f, 0.f, 0.f, 0.f, 0.f};
            const float4 d0 = ow4[ov][0];
            if (d0.w != 0.0f) {                   // voxel has any weight
                #pragma unroll
                for (int p = 0; p < 4; ++p) {
                    const float4 d = (p == 0) ? d0 : ow4[ov][p];
                    if (d.y == 0.0f && d.z == 0.0f) continue;   // pair weight 0
                    const int offp = __float_as_int(d.x);
                    const float w  = side ? d.z : d.y;
                    const uint4 fv = feat_h4[(size_t)offp * 4 + l];  // 16B
                    float2 f;
                    f = __half22float2(u2h(fv.x)); acc[0] += f.x * w; acc[1] += f.y * w;
                    f = __half22float2(u2h(fv.y)); acc[2] += f.x * w; acc[3] += f.y * w;
                    f = __half22float2(u2h(fv.z)); acc[4] += f.x * w; acc[5] += f.y * w;
                    f = __half22float2(u2h(fv.w)); acc[6] += f.x * w; acc[7] += f.y * w;
                }
            }
            #pragma unroll
            for (int k = 0; k < 8; ++k) acc[k] += __shfl_xor(acc[k], 4);
            if (side == 0) {
                #pragma unroll
                for (int k = 0; k < 8; ++k) tile[vl][cq * 8 + k] = acc[k];
            }
        }
        __syncthreads();

        // coalesced nontemporal float4 stores of this 128-voxel sub-tile
        #pragma unroll
        for (int it2 = 0; it2 < 4; ++it2) {
            const int idx = it2 * 256 + tid;
            const int v32 = idx & 31;
            const int c   = idx >> 5;
            nt_store4(&ob[(size_t)c * DHW + h * 128 + v32 * 4],
                      tile[v32 * 4 + 0][c], tile[v32 * 4 + 1][c],
                      tile[v32 * 4 + 2][c], tile[v32 * 4 + 3][c]);
        }
        __syncthreads();
    }
}

// --- Fallback (R1 kernel) if workspace is too small ---
__global__ __launch_bounds__(256) void proj_kernel(
    const float* __restrict__ feat,
    const float* __restrict__ sdf,
    const float* __restrict__ occ,
    const float* __restrict__ T12,
    float* __restrict__ out) {

    const int b   = blockIdx.x / (DHW / 256);
    const int rem = blockIdx.x % (DHW / 256);
    const int zyx = rem * 256 + threadIdx.x;
    const int x   = zyx % XD;
    const int t1  = zyx / XD;
    const int y   = t1 % YD;
    const int z   = t1 / YD;

    const float* Tb = T12 + b * 12;
    const float px = x * VOX, py = y * VOX, pz = z * VOX;
    const float hx = Tb[0] * px + Tb[1] * py + Tb[2]  * pz + Tb[3];
    const float hy = Tb[4] * px + Tb[5] * py + Tb[6]  * pz + Tb[7];
    const float hz = Tb[8] * px + Tb[9] * py + Tb[10] * pz + Tb[11];

    const float nx = 2.0f * ((hx / VOX) / 95.0f) - 1.0f;
    const float ny = 2.0f * ((hy / VOX) / 95.0f) - 1.0f;
    const float nz = 2.0f * ((hz / VOX) / 47.0f) - 1.0f;

    {
        const long long gbase = GRID_OFF + ((long long)b * DHW + zyx) * 3;
        out[gbase + 0] = nx;
        out[gbase + 1] = ny;
        out[gbase + 2] = nz;
    }

    const float ix = (nx + 1.0f) * 0.5f * 95.0f;
    const float iy = (ny + 1.0f) * 0.5f * 95.0f;
    const float iz = (nz + 1.0f) * 0.5f * 47.0f;

    const float x0f = floorf(ix), y0f = floorf(iy), z0f = floorf(iz);
    const float fx = ix - x0f, fy = iy - y0f, fz = iz - z0f;

    const float wXa[2] = {1.0f - fx, fx};
    const float wYa[2] = {1.0f - fy, fy};
    const float wZa[2] = {1.0f - fz, fz};

    int  cX[2], cY[2], cZ[2];
    bool vX[2], vY[2], vZ[2];
    #pragma unroll
    for (int d = 0; d < 2; ++d) {
        const float xi = x0f + (float)d;
        const float yi = y0f + (float)d;
        const float zi = z0f + (float)d;
        vX[d] = (xi >= 0.0f) && (xi <= 95.0f);
        vY[d] = (yi >= 0.0f) && (yi <= 95.0f);
        vZ[d] = (zi >= 0.0f) && (zi <= 47.0f);
        cX[d] = (int)fminf(fmaxf(xi, 0.0f), 95.0f);
        cY[d] = (int)fminf(fmaxf(yi, 0.0f), 95.0f);
        cZ[d] = (int)fminf(fmaxf(zi, 0.0f), 47.0f);
    }

    int   offs[8];
    float wts[8];
    #pragma unroll
    for (int j = 0; j < 8; ++j) {
        const int dx = (j >> 2) & 1, dy = (j >> 1) & 1, dz = j & 1;
        offs[j] = cZ[dz] * HW + cY[dy] * XD + cX[dx];
        float w = (wXa[dx] * wYa[dy]) * wZa[dz];
        wts[j] = (vX[dx] && vY[dy] && vZ[dz]) ? w : 0.0f;
    }

    const float* fb = feat + (long long)b * CD * DHW;
    float* ob = out + (long long)b * CD * DHW + zyx;
    #pragma unroll 4
    for (int cc = 0; cc < CD; ++cc) {
        const float* p = fb + (long long)cc * DHW;
        float acc = 0.0f;
        #pragma unroll
        for (int j = 0; j < 8; ++j) acc += p[offs[j]] * wts[j];
        ob[(long long)cc * DHW] = acc;
    }
    {
        const float* p = sdf + (long long)b * DHW;
        float acc = 0.0f;
        #pragma unroll
        for (int j = 0; j < 8; ++j) acc += p[offs[j]] * wts[j];
        out[FEAT_N + (long long)b * DHW + zyx] = acc;
    }
    {
        const float* p = occ + (long long)b * DHW;
        float acc = 0.0f;
        #pragma unroll
        for (int j = 0; j < 8; ++j) acc += p[offs[j]] * wts[j];
        out[FEAT_N + SDF_N + (long long)b * DHW + zyx] = acc;
    }
}

extern "C" void kernel_launch(void* const* d_in, const int* in_sizes, int n_in,
                              void* d_out, int out_size, void* d_ws, size_t ws_size,
                              hipStream_t stream) {
    const float* feat = (const float*)d_in[0];
    const float* sdf  = (const float*)d_in[1];
    const float* occ  = (const float*)d_in[2];
    const float* hist = (const float*)d_in[3];
    const float* cur  = (const float*)d_in[4];
    float* out = (float*)d_out;

    // ws layout: feat_h (FEAT_N halfs) | so_dup (B*DHW uint2) | T12
    const size_t feat_h_bytes = (size_t)FEAT_N * 2;                 // ~226.5 MB
    const size_t so_bytes     = (size_t)BD * DHW * sizeof(uint2);   // ~28.3 MB
    const size_t need         = feat_h_bytes + so_bytes + 512;

    if (ws_size >= need) {
        uint4* feat_h4 = (uint4*)d_ws;
        uint2* so_dup  = (uint2*)((char*)d_ws + feat_h_bytes);
        float* T12     = (float*)((char*)d_ws + feat_h_bytes + so_bytes);

        make_transform_kernel<<<1, BD, 0, stream>>>(hist, cur, T12);
        transpose_kernel<<<BD * ZD * YD, 256, 0, stream>>>(
            (const float4*)feat, sdf, occ, T12, feat_h4, so_dup);
        proj2_kernel<<<BD * (DHW / 256), 256, 0, stream>>>(
            (const uint4*)feat_h4, (const uint2*)so_dup, T12, out);
    } else {
        float* T12 = (float*)d_ws;
        make_transform_kernel<<<1, BD, 0, stream>>>(hist, cur, T12);
        proj_kernel<<<BD * (DHW / 256), 256, 0, stream>>>(feat, sdf, occ, T12, out);
    }
}